// Round 8
// baseline (1036.317 us; speedup 1.0000x reference)
//
#include <hip/hip_runtime.h>
#include <hip/hip_bf16.h>
#include <cstdint>

#define B_SZ   2048
#define D_INN  1024
#define H_SZ   2048
#define D_OUTN 1024
#define TMAX   12

typedef _Float16 f16;
typedef __attribute__((ext_vector_type(8))) _Float16 f16x8;
typedef __attribute__((ext_vector_type(4))) _Float16 f16x4;
typedef __attribute__((ext_vector_type(4))) float    f32x4;

typedef const __attribute__((address_space(1))) uint32_t* gptr_t;
typedef __attribute__((address_space(3))) uint32_t*       lptr_t;
__device__ inline void gld16(const void* g, void* l) {   // 16B global->LDS DMA
    __builtin_amdgcn_global_load_lds((gptr_t)g, (lptr_t)l, 16, 0, 0);
}

// ---------------------------------------------------------------------------
// Split-fp16 NT GEMM, 3-term Markidis: C ≈ Ahi·Bhi + Ahi·Blo + Alo·Bhi.
// Template <BM,BN>: 256 thr / 4 waves (2x2), wave tile (BM/2)x(BN/2) —
// fat waves cut LDS reads/MFMA by 25% vs the 8-wave 32x32 decomposition
// (LDS read BW was the binding pipe at round 7: conflicts 0, MfmaUtil 29%).
// 3 LDS buffers + counted s_waitcnt vmcnt(NV) (never 0 in-loop) + s_barrier;
// T2 XOR swizzle both-sides (read f16-off ^= ((row>>1)&3)<<3, source chunk
// c ^= (c>>3)&3). XCD-chunked bijective blockIdx swizzle (nwg%8==0).
// Epilogue: +Cadd, +radd; writes Cf and/or (Chi,Clo); optional fused
// per-row halt-dot partials: dots[row][nt] = Σ_cols v·w_halt[col]
// (computed from fp32 acc in-registers — deterministic, no extra traffic).
// ---------------------------------------------------------------------------
template<int BM, int BN>
__global__ __launch_bounds__(256, 3) void gemm_split(
    const f16* __restrict__ Ahi, const f16* __restrict__ Alo, int lda,
    const f16* __restrict__ Bhi, const f16* __restrict__ Blo, int ldb,
    const float* __restrict__ Cadd,   // optional [M,ldc] fp32
    const float* __restrict__ radd,   // optional [N] fp32
    float* __restrict__ Cf,           // optional fp32 out
    f16* __restrict__ Chi, f16* __restrict__ Clo,  // optional fp16 pair out
    int ldc, int K, int nx,
    float* __restrict__ dots,         // optional [M][nx] halt-dot partials
    const float* __restrict__ w_halt) // [N] when dots != null
{
    constexpr int RW = 2, CW = 2;
    constexpr int WM = BM / (16 * RW);      // m-frags per wave
    constexpr int WN = BN / (16 * CW);      // n-frags per wave
    constexpr int LA = BM / 64;             // A chunks/thread (each of hi,lo)
    constexpr int LB = BN / 64;
    constexpr int NV = 2 * (LA + LB);       // vmem loads/thread/K-step
    constexpr int ASZ = BM * 32;            // f16 per A buffer
    constexpr int BSZ = BN * 32;

    __shared__ __align__(16) f16 Ash[3][ASZ];
    __shared__ __align__(16) f16 Asl[3][ASZ];
    __shared__ __align__(16) f16 Bsh[3][BSZ];
    __shared__ __align__(16) f16 Bsl[3][BSZ];
    __shared__ float dred[CW][BM];

    const int tid  = threadIdx.x;
    const int wave = tid >> 6;
    const int lane = tid & 63;

    // XCD-chunked bijective blockIdx swizzle (requires nwg % 8 == 0)
    const int nwg = gridDim.x;
    const int cpx = nwg >> 3;
    const int bid = (blockIdx.x & 7) * cpx + (blockIdx.x >> 3);
    const int m0 = (bid / nx) * BM, n0 = (bid % nx) * BN;

    const int wr = wave >> 1, wc = wave & 1;      // 2x2 wave grid
    const int fr = lane & 15, fq = lane >> 4;     // fragment row / k-group

    // staging: chunk c (16B) -> LDS f16-offset c*8 (linear);
    // global source chunk swizzled by the involution c ^ ((c>>3)&3)
    size_t aOff[LA]; int aDst[LA];
#pragma unroll
    for (int i = 0; i < LA; ++i) {
        const int c = i * 256 + tid;
        const int cs = c ^ ((c >> 3) & 3);
        aOff[i] = (size_t)(m0 + (cs >> 2)) * lda + (cs & 3) * 8;
        aDst[i] = (i * 256 + wave * 64) * 8;   // wave-uniform base; HW adds lane*16B
    }
    size_t bOff[LB]; int bDst[LB];
#pragma unroll
    for (int i = 0; i < LB; ++i) {
        const int c = i * 256 + tid;
        const int cs = c ^ ((c >> 3) & 3);
        bOff[i] = (size_t)(n0 + (cs >> 2)) * ldb + (cs & 3) * 8;
        bDst[i] = (i * 256 + wave * 64) * 8;
    }

    auto STAGE = [&](int buf, int k0) {
#pragma unroll
        for (int i = 0; i < LA; ++i) {
            gld16(Ahi + aOff[i] + k0, &Ash[buf][aDst[i]]);
            gld16(Alo + aOff[i] + k0, &Asl[buf][aDst[i]]);
        }
#pragma unroll
        for (int i = 0; i < LB; ++i) {
            gld16(Bhi + bOff[i] + k0, &Bsh[buf][bDst[i]]);
            gld16(Blo + bOff[i] + k0, &Bsl[buf][bDst[i]]);
        }
    };

    // swizzled k-invariant fragment read offsets (f16 units)
    int offA[WM], offB[WN];
#pragma unroll
    for (int m = 0; m < WM; ++m) {
        const int row = wr * (WM * 16) + m * 16 + fr;
        offA[m] = row * 32 + ((fq ^ ((row >> 1) & 3)) << 3);
    }
#pragma unroll
    for (int n = 0; n < WN; ++n) {
        const int row = wc * (WN * 16) + n * 16 + fr;
        offB[n] = row * 32 + ((fq ^ ((row >> 1) & 3)) << 3);
    }

    f32x4 acc[WM][WN] = {};

    STAGE(0, 0);
    const int nk = K >> 5;
    int cur = 0;
    for (int ki = 0; ki < nk; ++ki) {
        const int nxt = (cur == 2) ? 0 : cur + 1;
        if (ki + 1 < nk) {
            STAGE(nxt, (ki + 1) << 5);
            asm volatile("s_waitcnt vmcnt(%0)" :: "i"(NV) : "memory");
        } else {
            asm volatile("s_waitcnt vmcnt(0)" ::: "memory");
        }
        __builtin_amdgcn_s_barrier();
        asm volatile("" ::: "memory");   // keep ds_reads below the barrier

        f16x8 ah[WM], al[WM], bh[WN], bl[WN];
#pragma unroll
        for (int m = 0; m < WM; ++m) {
            ah[m] = *(const f16x8*)(&Ash[cur][offA[m]]);
            al[m] = *(const f16x8*)(&Asl[cur][offA[m]]);
        }
#pragma unroll
        for (int n = 0; n < WN; ++n) {
            bh[n] = *(const f16x8*)(&Bsh[cur][offB[n]]);
            bl[n] = *(const f16x8*)(&Bsl[cur][offB[n]]);
        }
#pragma unroll
        for (int m = 0; m < WM; ++m)
#pragma unroll
            for (int n = 0; n < WN; ++n)
                acc[m][n] = __builtin_amdgcn_mfma_f32_16x16x32_f16(
                    ah[m], bh[n], acc[m][n], 0, 0, 0);
#pragma unroll
        for (int m = 0; m < WM; ++m)
#pragma unroll
            for (int n = 0; n < WN; ++n)
                acc[m][n] = __builtin_amdgcn_mfma_f32_16x16x32_f16(
                    ah[m], bl[n], acc[m][n], 0, 0, 0);
#pragma unroll
        for (int m = 0; m < WM; ++m)
#pragma unroll
            for (int n = 0; n < WN; ++n)
                acc[m][n] = __builtin_amdgcn_mfma_f32_16x16x32_f16(
                    al[m], bh[n], acc[m][n], 0, 0, 0);
        cur = nxt;
    }

    // epilogue. C/D layout: col = lane&15, row = (lane>>4)*4 + reg
    float whv[WN];
    float pd[WM][4];
    if (dots) {
#pragma unroll
        for (int n = 0; n < WN; ++n)
            whv[n] = w_halt[n0 + wc * (WN * 16) + n * 16 + fr];
#pragma unroll
        for (int m = 0; m < WM; ++m)
#pragma unroll
            for (int r = 0; r < 4; ++r) pd[m][r] = 0.f;
    }

#pragma unroll
    for (int m = 0; m < WM; ++m) {
#pragma unroll
        for (int n = 0; n < WN; ++n) {
#pragma unroll
            for (int r = 0; r < 4; ++r) {
                const int row = m0 + wr * (WM * 16) + m * 16 + fq * 4 + r;
                const int col = n0 + wc * (WN * 16) + n * 16 + fr;
                float v = acc[m][n][r];
                if (Cadd) v += Cadd[(size_t)row * ldc + col];
                if (radd) v += radd[col];
                if (Cf) Cf[(size_t)row * ldc + col] = v;
                if (Chi) {
                    const f16 hi = (f16)v;
                    Chi[(size_t)row * ldc + col] = hi;
                    Clo[(size_t)row * ldc + col] = (f16)(v - (float)hi);
                }
                if (dots) pd[m][r] += v * whv[n];
            }
        }
    }

    if (dots) {
        // reduce over the 16-lane fr-group (masks <16 stay within group)
#pragma unroll
        for (int mask = 1; mask < 16; mask <<= 1)
#pragma unroll
            for (int m = 0; m < WM; ++m)
#pragma unroll
                for (int r = 0; r < 4; ++r)
                    pd[m][r] += __shfl_xor(pd[m][r], mask, 64);
        if (fr == 0) {
#pragma unroll
            for (int m = 0; m < WM; ++m)
#pragma unroll
                for (int r = 0; r < 4; ++r)
                    dred[wc][wr * (WM * 16) + m * 16 + fq * 4 + r] = pd[m][r];
        }
        __syncthreads();
        if (tid < BM) {
            float s = 0.f;
#pragma unroll
            for (int w = 0; w < CW; ++w) s += dred[w][tid];
            dots[(size_t)(m0 + tid) * nx + (bid % nx)] = s;
        }
    }
}

// strided fp32 [rows,cols] (ld) -> contiguous fp16 (hi, lo) pair
__global__ __launch_bounds__(256) void split2d(
    const float* __restrict__ src, int ld, int cols,
    f16* __restrict__ hi, f16* __restrict__ lo, int total4)
{
    const int i = blockIdx.x * 256 + threadIdx.x;
    if (i >= total4) return;
    const int idx = i * 4;
    const int r = idx / cols, c = idx % cols;
    const float4 v = *(const float4*)(src + (size_t)r * ld + c);
    f16x4 h, l;
    h[0] = (f16)v.x; l[0] = (f16)(v.x - (float)h[0]);
    h[1] = (f16)v.y; l[1] = (f16)(v.y - (float)h[1]);
    h[2] = (f16)v.z; l[2] = (f16)(v.z - (float)h[2]);
    h[3] = (f16)v.w; l[3] = (f16)(v.w - (float)h[3]);
    *(f16x4*)(hi + idx) = h;
    *(f16x4*)(lo + idx) = l;
}

// rsum[j] = sum_{k<K} W[j,k]   (the (x+1)-vs-x correction for t==0), fp32
__global__ __launch_bounds__(256) void rowsum_kernel(
    const float* __restrict__ W, int ld, int K, float* __restrict__ out)
{
    const int j = blockIdx.x;
    const int tid = threadIdx.x;
    float s = 0.f;
    for (int k = tid; k < K; k += 256) s += W[(size_t)j * ld + k];
#pragma unroll
    for (int off = 32; off; off >>= 1) s += __shfl_down(s, off);
    __shared__ float red[4];
    if ((tid & 63) == 0) red[tid >> 6] = s;
    __syncthreads();
    if (tid == 0) out[j] = red[0] + red[1] + red[2] + red[3];
}

// Per-step ACT halting + hidden accumulation, one block per batch row.
// The halt dot comes precomputed (GEMM-epilogue partials, fp32, deterministic
// fixed-order sum) — halted rows exit after a 64-B read; s read is hi-only
// (hidden tolerance is ~bf16: error 2^-11 ≪ 0.2587 threshold).
__global__ __launch_bounds__(256) void halt_hid(
    const f16* __restrict__ s_hi,      // [B,H] fp16 hi
    const float* __restrict__ dots,    // [B][16] partial dots
    const float* __restrict__ b_halt,  // [1]
    float* __restrict__ hidden,        // [B,H] accumulator (in d_out)
    float* __restrict__ ponder,        // [B]   (in d_out)
    float* __restrict__ cumB,          // [B] state
    float* __restrict__ Rv,            // [B] state
    float* __restrict__ nstep,         // [B] state
    int*   __restrict__ halted,        // [B] state
    int t)
{
    const int b = blockIdx.x;
    const int tid = threadIdx.x;
    __shared__ float w_sh;
    if (tid == 0) {
        float d = b_halt[0];
#pragma unroll
        for (int i = 0; i < 16; ++i) d += dots[(size_t)b * 16 + i];
        const float p = 1.f / (1.f + expf(-d));
        const float cb = (t == 0) ? 0.f : cumB[b];
        const int   hd = (t == 0) ? 0   : halted[b];
        float w;
        if (hd) {
            w = 0.f;
        } else if (cb + p >= 0.99f || t == TMAX - 1) {
            w = 1.f - cb;                 // remainder R
            halted[b] = 1;
            Rv[b] = w;
            nstep[b] = (float)t;
        } else {
            w = p;
            cumB[b] = cb + p;
            if (t == 0) halted[b] = 0;
        }
        w_sh = w;
        if (t == TMAX - 1) ponder[b] = nstep[b] + 1.f + Rv[b];
    }
    __syncthreads();
    const float w = w_sh;
    if (t > 0 && w == 0.f) return;        // halted rows contribute nothing

    const f16x8 vh = *(const f16x8*)(s_hi + (size_t)b * H_SZ + tid * 8);
    float s[8];
#pragma unroll
    for (int j = 0; j < 8; ++j) s[j] = (float)vh[j];
    float* hrow = hidden + (size_t)b * H_SZ + tid * 8;
    if (t == 0) {
#pragma unroll
        for (int j = 0; j < 8; ++j) hrow[j] = w * s[j];
    } else {
        float4 h0 = *(const float4*)(hrow);
        float4 h1 = *(const float4*)(hrow + 4);
        h0.x += w * s[0]; h0.y += w * s[1]; h0.z += w * s[2]; h0.w += w * s[3];
        h1.x += w * s[4]; h1.y += w * s[5]; h1.z += w * s[6]; h1.w += w * s[7];
        *(float4*)(hrow)     = h0;
        *(float4*)(hrow + 4) = h1;
    }
}

extern "C" void kernel_launch(void* const* d_in, const int* in_sizes, int n_in,
                              void* d_out, int out_size, void* d_ws, size_t ws_size,
                              hipStream_t stream)
{
    const float* x        = (const float*)d_in[0];   // [B, D_IN]
    const float* h        = (const float*)d_in[1];   // [B, H]
    const float* W_hidden = (const float*)d_in[2];   // [H, D_IN+H]
    const float* b_hidden = (const float*)d_in[3];   // [H]
    const float* w_halt   = (const float*)d_in[4];   // [H]
    const float* b_halt   = (const float*)d_in[5];   // [1]
    const float* W_out    = (const float*)d_in[6];   // [D_OUT, H]
    const float* b_out    = (const float*)d_in[7];   // [D_OUT]

    float* out    = (float*)d_out;
    float* output = out;                                   // [B, D_OUT]
    float* hidden = out + (size_t)B_SZ * D_OUTN;           // [B, H]
    float* ponder = hidden + (size_t)B_SZ * H_SZ;          // [B]

    // ---- workspace layout ----
    float* ws     = (float*)d_ws;
    float* xc     = ws;                                    // [B,H] fp32 16MB
    float* rsum   = xc + (size_t)B_SZ * H_SZ;              // [H]
    float* cumB   = rsum + H_SZ;                           // [B]
    float* Rv     = cumB + B_SZ;                           // [B]
    float* nstep  = Rv + B_SZ;                             // [B]
    int*   halted = (int*)(nstep + B_SZ);                  // [B]
    float* dots   = (float*)(halted + B_SZ);               // [B][16] 128KB
    f16*   fh     = (f16*)(dots + (size_t)B_SZ * 16);
    f16* xh  = fh;                         // [B,D_IN]  4MB
    f16* xl  = xh  + (size_t)B_SZ * D_INN; // 4MB
    f16* sh0 = xl  + (size_t)B_SZ * D_INN; // [B,H] 8MB
    f16* sl0 = sh0 + (size_t)B_SZ * H_SZ;
    f16* sh1 = sl0 + (size_t)B_SZ * H_SZ;
    f16* sl1 = sh1 + (size_t)B_SZ * H_SZ;
    f16* Wxh = sl1 + (size_t)B_SZ * H_SZ;  // [H,D_IN] 4MB
    f16* Wxl = Wxh + (size_t)H_SZ * D_INN;
    f16* Wsh = Wxl + (size_t)H_SZ * D_INN; // [H,H] 8MB
    f16* Wsl = Wsh + (size_t)H_SZ * H_SZ;
    f16* Woh = Wsl + (size_t)H_SZ * H_SZ;  // [D_OUT,H] 4MB
    f16* Wol = Woh + (size_t)D_OUTN * H_SZ;
    f16* hidh = sh0;                       // reuse after the t-loop
    f16* hidl = sl0;

    const dim3 blk(256);
    const int LDW = D_INN + H_SZ;  // 3072

    // one-time fp32 -> fp16 (hi,lo) splits
    split2d<<<dim3(B_SZ * D_INN / 4 / 256), blk, 0, stream>>>(
        x, D_INN, D_INN, xh, xl, B_SZ * D_INN / 4);
    split2d<<<dim3(B_SZ * H_SZ / 4 / 256), blk, 0, stream>>>(
        h, H_SZ, H_SZ, sh0, sl0, B_SZ * H_SZ / 4);
    split2d<<<dim3(H_SZ * D_INN / 4 / 256), blk, 0, stream>>>(
        W_hidden, LDW, D_INN, Wxh, Wxl, H_SZ * D_INN / 4);
    split2d<<<dim3(H_SZ * H_SZ / 4 / 256), blk, 0, stream>>>(
        W_hidden + D_INN, LDW, H_SZ, Wsh, Wsl, H_SZ * H_SZ / 4);
    split2d<<<dim3(D_OUTN * H_SZ / 4 / 256), blk, 0, stream>>>(
        W_out, H_SZ, H_SZ, Woh, Wol, D_OUTN * H_SZ / 4);

    // rsum[j] = sum_k W_x[j,k]   (xin = x+1 correction at t==0)
    rowsum_kernel<<<dim3(H_SZ), blk, 0, stream>>>(W_hidden, LDW, D_INN, rsum);

    // grids (1-D, XCD-swizzled in-kernel; all % 8 == 0)
    const int g_step = (B_SZ / 64) * (H_SZ / 128);    // 32*16 = 512
    const int g_out  = (B_SZ / 64) * (D_OUTN / 64);   // 32*16 = 512

    // xc = x @ W_x^T + b_hidden   (loop-invariant part, fp32)
    gemm_split<64, 128><<<dim3(g_step), blk, 0, stream>>>(
        xh, xl, D_INN, Wxh, Wxl, D_INN, nullptr, b_hidden,
        xc, nullptr, nullptr, H_SZ, D_INN, H_SZ / 128, nullptr, nullptr);

    for (int t = 0; t < TMAX; ++t) {
        const f16* ph = (t & 1) ? sh1 : sh0;
        const f16* pl = (t & 1) ? sl1 : sl0;
        f16*       nh = (t & 1) ? sh0 : sh1;
        f16*       nl = (t & 1) ? sl0 : sl1;
        // s_new = s_prev @ W_s^T + xc (+ rsum at t==0); fused halt-dot partials
        gemm_split<64, 128><<<dim3(g_step), blk, 0, stream>>>(
            ph, pl, H_SZ, Wsh, Wsl, H_SZ, xc, (t == 0) ? rsum : nullptr,
            nullptr, nh, nl, H_SZ, H_SZ, H_SZ / 128, dots, w_halt);
        halt_hid<<<dim3(B_SZ), blk, 0, stream>>>(
            nh, dots, b_halt, hidden, ponder, cumB, Rv, nstep, halted, t);
    }

    // output = hidden @ W_out^T + b_out   (Σw = 1 ⇒ projection commutes)
    split2d<<<dim3(B_SZ * H_SZ / 4 / 256), blk, 0, stream>>>(
        hidden, H_SZ, H_SZ, hidh, hidl, B_SZ * H_SZ / 4);
    gemm_split<64, 64><<<dim3(g_out), blk, 0, stream>>>(
        hidh, hidl, H_SZ, Woh, Wol, H_SZ, nullptr, b_out,
        output, nullptr, nullptr, D_OUTN, H_SZ, D_OUTN / 64, nullptr, nullptr);
}

// Round 9
// 973.504 us; speedup vs baseline: 1.0645x; 1.0645x over previous
//
#include <hip/hip_runtime.h>
#include <hip/hip_bf16.h>
#include <cstdint>

#define B_SZ   2048
#define D_INN  1024
#define H_SZ   2048
#define D_OUTN 1024
#define TMAX   12

typedef _Float16 f16;
typedef __attribute__((ext_vector_type(8))) _Float16 f16x8;
typedef __attribute__((ext_vector_type(4))) _Float16 f16x4;
typedef __attribute__((ext_vector_type(4))) float    f32x4;

typedef const __attribute__((address_space(1))) uint32_t* gptr_t;
typedef __attribute__((address_space(3))) uint32_t*       lptr_t;
__device__ inline void gld16(const void* g, void* l) {   // 16B global->LDS DMA
    __builtin_amdgcn_global_load_lds((gptr_t)g, (lptr_t)l, 16, 0, 0);
}

// ---------------------------------------------------------------------------
// Split-fp16 NT GEMM, 3-term Markidis: C ≈ Ahi·Bhi + Ahi·Blo + Alo·Bhi.
// BM=128 fixed; 512 thr / 8 waves, wave grid 4x2 -> wave tile 32 x (BN/2).
// Rationale (r7/r8 counters): LDS read BW is the binding pipe; reads scale
// as (Wr+Wc), FLOPs as Wr*Wc -> fat 32x64 waves at 8 waves/block gives
// LDS:MFMA 1.65:1 (vs 4.4:1 at r7's 32x32) while keeping 2 waves/SIMD.
// 3 LDS buffers (96KB, 1 block/CU) + counted s_waitcnt vmcnt(NV) (never 0
// in-loop) + raw s_barrier; T2 XOR swizzle both-sides (verified: 0 conflicts).
// XCD-chunked bijective blockIdx swizzle (nwg%8==0).
// Epilogue: +Cadd, +radd; writes Cf and/or (Chi,Clo); optional fused per-row
// halt-dot partials from the fp32 accumulator (deterministic fixed order).
// ---------------------------------------------------------------------------
template<int BM, int BN, int MW>
__global__ __launch_bounds__(512, MW) void gemm_split(
    const f16* __restrict__ Ahi, const f16* __restrict__ Alo, int lda,
    const f16* __restrict__ Bhi, const f16* __restrict__ Blo, int ldb,
    const float* __restrict__ Cadd,   // optional [M,ldc] fp32
    const float* __restrict__ radd,   // optional [N] fp32
    float* __restrict__ Cf,           // optional fp32 out
    f16* __restrict__ Chi, f16* __restrict__ Clo,  // optional fp16 pair out
    int ldc, int K, int nx,
    float* __restrict__ dots,         // optional [M][nx] halt-dot partials
    const float* __restrict__ w_halt) // [N] when dots != null
{
    static_assert(BM == 128, "");
    constexpr int WM = 2;                   // m-frags/wave (32 rows)
    constexpr int WN = BN / 32;             // n-frags/wave (BN/2 cols)
    constexpr int CB = BN * 4;              // 16B chunks per B tensor
    constexpr int NV = (CB == 512) ? 4 : 3; // vmem loads/thread/K-step
    constexpr int ASZ = BM * 32;            // f16 per A buffer
    constexpr int BSZ = BN * 32;

    __shared__ __align__(16) f16 Ash[3][ASZ];
    __shared__ __align__(16) f16 Asl[3][ASZ];
    __shared__ __align__(16) f16 Bsh[3][BSZ];
    __shared__ __align__(16) f16 Bsl[3][BSZ];
    __shared__ float dred[2][BM];

    const int tid  = threadIdx.x;
    const int wave = tid >> 6;
    const int lane = tid & 63;

    // XCD-chunked bijective blockIdx swizzle (requires nwg % 8 == 0)
    const int nwg = gridDim.x;
    const int cpx = nwg >> 3;
    const int bid = (blockIdx.x & 7) * cpx + (blockIdx.x >> 3);
    const int m0 = (bid / nx) * BM, n0 = (bid % nx) * BN;

    const int wr = wave >> 1, wc = wave & 1;      // 4x2 wave grid
    const int fr = lane & 15, fq = lane >> 4;     // fragment row / k-group

    // --- staging: LDS dest linear 16B chunks; global source chunk swizzled
    //     by the involution c ^= ((c>>3)&3) (== read byte ^ ((row>>1)&3)<<4)
    // A: 512 chunks each (hi & lo), 1 per thread
    const int acs = tid ^ ((tid >> 3) & 3);
    const size_t aOff = (size_t)(m0 + (acs >> 2)) * lda + (acs & 3) * 8;
    const int aDst = wave << 9;   // wave-uniform base; HW adds lane*16B
    // B: CB chunks each of hi/lo
    int bcs;  size_t bOffH, bOffL;  int bDst;
    if constexpr (CB == 512) {
        bcs = tid ^ ((tid >> 3) & 3);
        bOffH = bOffL = (size_t)(n0 + (bcs >> 2)) * ldb + (bcs & 3) * 8;
        bDst = wave << 9;
    } else {        // CB == 256: waves 0-3 -> Bhi, waves 4-7 -> Blo
        const int c = tid & 255;
        bcs = c ^ ((c >> 3) & 3);
        bOffH = bOffL = (size_t)(n0 + (bcs >> 2)) * ldb + (bcs & 3) * 8;
        bDst = (wave & 3) << 9;
    }

    auto STAGE = [&](int buf, int k0) {
        gld16(Ahi + aOff + k0, &Ash[buf][aDst]);
        gld16(Alo + aOff + k0, &Asl[buf][aDst]);
        if constexpr (CB == 512) {
            gld16(Bhi + bOffH + k0, &Bsh[buf][bDst]);
            gld16(Blo + bOffL + k0, &Bsl[buf][bDst]);
        } else {
            if (wave < 4) gld16(Bhi + bOffH + k0, &Bsh[buf][bDst]);
            else          gld16(Blo + bOffL + k0, &Bsl[buf][bDst]);
        }
    };

    // swizzled k-invariant fragment read offsets (f16 units)
    int offA[WM], offB[WN];
#pragma unroll
    for (int m = 0; m < WM; ++m) {
        const int row = wr * 32 + m * 16 + fr;
        offA[m] = row * 32 + ((fq ^ ((row >> 1) & 3)) << 3);
    }
#pragma unroll
    for (int n = 0; n < WN; ++n) {
        const int row = wc * (WN * 16) + n * 16 + fr;
        offB[n] = row * 32 + ((fq ^ ((row >> 1) & 3)) << 3);
    }

    f32x4 acc[WM][WN] = {};

    STAGE(0, 0);
    const int nk = K >> 5;
    int cur = 0;
    for (int ki = 0; ki < nk; ++ki) {
        const int nxt = (cur == 2) ? 0 : cur + 1;
        if (ki + 1 < nk) {
            STAGE(nxt, (ki + 1) << 5);
            asm volatile("s_waitcnt vmcnt(%0)" :: "i"(NV) : "memory");
        } else {
            asm volatile("s_waitcnt vmcnt(0)" ::: "memory");
        }
        __builtin_amdgcn_s_barrier();
        asm volatile("" ::: "memory");   // keep ds_reads below the barrier

        f16x8 ah[WM], al[WM], bh[WN], bl[WN];
#pragma unroll
        for (int m = 0; m < WM; ++m) {
            ah[m] = *(const f16x8*)(&Ash[cur][offA[m]]);
            al[m] = *(const f16x8*)(&Asl[cur][offA[m]]);
        }
#pragma unroll
        for (int n = 0; n < WN; ++n) {
            bh[n] = *(const f16x8*)(&Bsh[cur][offB[n]]);
            bl[n] = *(const f16x8*)(&Bsl[cur][offB[n]]);
        }
#pragma unroll
        for (int m = 0; m < WM; ++m)
#pragma unroll
            for (int n = 0; n < WN; ++n)
                acc[m][n] = __builtin_amdgcn_mfma_f32_16x16x32_f16(
                    ah[m], bh[n], acc[m][n], 0, 0, 0);
#pragma unroll
        for (int m = 0; m < WM; ++m)
#pragma unroll
            for (int n = 0; n < WN; ++n)
                acc[m][n] = __builtin_amdgcn_mfma_f32_16x16x32_f16(
                    ah[m], bl[n], acc[m][n], 0, 0, 0);
#pragma unroll
        for (int m = 0; m < WM; ++m)
#pragma unroll
            for (int n = 0; n < WN; ++n)
                acc[m][n] = __builtin_amdgcn_mfma_f32_16x16x32_f16(
                    al[m], bh[n], acc[m][n], 0, 0, 0);
        cur = nxt;
    }

    // epilogue. C/D layout: col = lane&15, row = (lane>>4)*4 + reg
    float whv[WN];
    float pd[WM][4];
    if (dots) {
#pragma unroll
        for (int n = 0; n < WN; ++n)
            whv[n] = w_halt[n0 + wc * (WN * 16) + n * 16 + fr];
#pragma unroll
        for (int m = 0; m < WM; ++m)
#pragma unroll
            for (int r = 0; r < 4; ++r) pd[m][r] = 0.f;
    }

#pragma unroll
    for (int m = 0; m < WM; ++m) {
#pragma unroll
        for (int n = 0; n < WN; ++n) {
#pragma unroll
            for (int r = 0; r < 4; ++r) {
                const int row = m0 + wr * 32 + m * 16 + fq * 4 + r;
                const int col = n0 + wc * (WN * 16) + n * 16 + fr;
                float v = acc[m][n][r];
                if (Cadd) v += Cadd[(size_t)row * ldc + col];
                if (radd) v += radd[col];
                if (Cf) Cf[(size_t)row * ldc + col] = v;
                if (Chi) {
                    const f16 hi = (f16)v;
                    Chi[(size_t)row * ldc + col] = hi;
                    Clo[(size_t)row * ldc + col] = (f16)(v - (float)hi);
                }
                if (dots) pd[m][r] += v * whv[n];
            }
        }
    }

    if (dots) {
        // reduce over the 16-lane fr-group (masks <16 stay within group)
#pragma unroll
        for (int mask = 1; mask < 16; mask <<= 1)
#pragma unroll
            for (int m = 0; m < WM; ++m)
#pragma unroll
                for (int r = 0; r < 4; ++r)
                    pd[m][r] += __shfl_xor(pd[m][r], mask, 64);
        if (fr == 0) {
#pragma unroll
            for (int m = 0; m < WM; ++m)
#pragma unroll
                for (int r = 0; r < 4; ++r)
                    dred[wc][wr * 32 + m * 16 + fq * 4 + r] = pd[m][r];
        }
        __syncthreads();
        if (tid < BM) {
            dots[(size_t)(m0 + tid) * nx + (bid % nx)] =
                dred[0][tid] + dred[1][tid];
        }
    }
}

// strided fp32 [rows,cols] (ld) -> contiguous fp16 (hi, lo) pair
__global__ __launch_bounds__(256) void split2d(
    const float* __restrict__ src, int ld, int cols,
    f16* __restrict__ hi, f16* __restrict__ lo, int total4)
{
    const int i = blockIdx.x * 256 + threadIdx.x;
    if (i >= total4) return;
    const int idx = i * 4;
    const int r = idx / cols, c = idx % cols;
    const float4 v = *(const float4*)(src + (size_t)r * ld + c);
    f16x4 h, l;
    h[0] = (f16)v.x; l[0] = (f16)(v.x - (float)h[0]);
    h[1] = (f16)v.y; l[1] = (f16)(v.y - (float)h[1]);
    h[2] = (f16)v.z; l[2] = (f16)(v.z - (float)h[2]);
    h[3] = (f16)v.w; l[3] = (f16)(v.w - (float)h[3]);
    *(f16x4*)(hi + idx) = h;
    *(f16x4*)(lo + idx) = l;
}

// rsum[j] = sum_{k<K} W[j,k]   (the (x+1)-vs-x correction for t==0), fp32
__global__ __launch_bounds__(256) void rowsum_kernel(
    const float* __restrict__ W, int ld, int K, float* __restrict__ out)
{
    const int j = blockIdx.x;
    const int tid = threadIdx.x;
    float s = 0.f;
    for (int k = tid; k < K; k += 256) s += W[(size_t)j * ld + k];
#pragma unroll
    for (int off = 32; off; off >>= 1) s += __shfl_down(s, off);
    __shared__ float red[4];
    if ((tid & 63) == 0) red[tid >> 6] = s;
    __syncthreads();
    if (tid == 0) out[j] = red[0] + red[1] + red[2] + red[3];
}

// Per-step ACT halting + hidden accumulation, one block per batch row.
// Halt dot precomputed in the GEMM epilogue (fp32, deterministic order).
// At t==TMAX-1 also emits the fp16 (hi,lo) split of the final hidden row
// (replaces the separate split2d pass). NOTE: s_hi may alias hidh — plain
// pointers (no __restrict__) and thread-local read-then-write ordering.
__global__ __launch_bounds__(256) void halt_hid(
    const f16* s_hi,                   // [B,H] fp16 hi of s_new
    const float* __restrict__ dots,    // [B][16] partial dots
    const float* __restrict__ b_halt,  // [1]
    float* hidden,                     // [B,H] accumulator (in d_out)
    float* __restrict__ ponder,        // [B]   (in d_out)
    float* __restrict__ cumB,          // [B] state
    float* __restrict__ Rv,            // [B] state
    float* __restrict__ nstep,         // [B] state
    int*   __restrict__ halted,        // [B] state
    f16* hidh, f16* hidl,              // written at t==TMAX-1
    int t)
{
    const int b = blockIdx.x;
    const int tid = threadIdx.x;
    __shared__ float w_sh;
    if (tid == 0) {
        float d = b_halt[0];
#pragma unroll
        for (int i = 0; i < 16; ++i) d += dots[(size_t)b * 16 + i];
        const float p = 1.f / (1.f + expf(-d));
        const float cb = (t == 0) ? 0.f : cumB[b];
        const int   hd = (t == 0) ? 0   : halted[b];
        float w;
        if (hd) {
            w = 0.f;
        } else if (cb + p >= 0.99f || t == TMAX - 1) {
            w = 1.f - cb;                 // remainder R
            halted[b] = 1;
            Rv[b] = w;
            nstep[b] = (float)t;
        } else {
            w = p;
            cumB[b] = cb + p;
            if (t == 0) halted[b] = 0;
        }
        w_sh = w;
        if (t == TMAX - 1) ponder[b] = nstep[b] + 1.f + Rv[b];
    }
    __syncthreads();
    const float w = w_sh;
    const bool skip = (t > 0 && w == 0.f);   // halted rows contribute nothing

    float* hrow = hidden + (size_t)b * H_SZ + tid * 8;
    float hv[8];
    if (!skip) {
        const f16x8 vh = *(const f16x8*)(s_hi + (size_t)b * H_SZ + tid * 8);
        if (t == 0) {
#pragma unroll
            for (int j = 0; j < 8; ++j) hv[j] = w * (float)vh[j];
        } else {
            const float4 h0 = *(const float4*)(hrow);
            const float4 h1 = *(const float4*)(hrow + 4);
            hv[0] = h0.x + w * (float)vh[0]; hv[1] = h0.y + w * (float)vh[1];
            hv[2] = h0.z + w * (float)vh[2]; hv[3] = h0.w + w * (float)vh[3];
            hv[4] = h1.x + w * (float)vh[4]; hv[5] = h1.y + w * (float)vh[5];
            hv[6] = h1.z + w * (float)vh[6]; hv[7] = h1.w + w * (float)vh[7];
        }
        *(float4*)(hrow)     = make_float4(hv[0], hv[1], hv[2], hv[3]);
        *(float4*)(hrow + 4) = make_float4(hv[4], hv[5], hv[6], hv[7]);
    }
    if (t == TMAX - 1) {
        if (skip) {
            const float4 h0 = *(const float4*)(hrow);
            const float4 h1 = *(const float4*)(hrow + 4);
            hv[0] = h0.x; hv[1] = h0.y; hv[2] = h0.z; hv[3] = h0.w;
            hv[4] = h1.x; hv[5] = h1.y; hv[6] = h1.z; hv[7] = h1.w;
        }
        f16x8 hh, hl;
#pragma unroll
        for (int j = 0; j < 8; ++j) {
            const f16 hi = (f16)hv[j];
            hh[j] = hi;
            hl[j] = (f16)(hv[j] - (float)hi);
        }
        *(f16x8*)(hidh + (size_t)b * H_SZ + tid * 8) = hh;
        *(f16x8*)(hidl + (size_t)b * H_SZ + tid * 8) = hl;
    }
}

extern "C" void kernel_launch(void* const* d_in, const int* in_sizes, int n_in,
                              void* d_out, int out_size, void* d_ws, size_t ws_size,
                              hipStream_t stream)
{
    const float* x        = (const float*)d_in[0];   // [B, D_IN]
    const float* h        = (const float*)d_in[1];   // [B, H]
    const float* W_hidden = (const float*)d_in[2];   // [H, D_IN+H]
    const float* b_hidden = (const float*)d_in[3];   // [H]
    const float* w_halt   = (const float*)d_in[4];   // [H]
    const float* b_halt   = (const float*)d_in[5];   // [1]
    const float* W_out    = (const float*)d_in[6];   // [D_OUT, H]
    const float* b_out    = (const float*)d_in[7];   // [D_OUT]

    float* out    = (float*)d_out;
    float* output = out;                                   // [B, D_OUT]
    float* hidden = out + (size_t)B_SZ * D_OUTN;           // [B, H]
    float* ponder = hidden + (size_t)B_SZ * H_SZ;          // [B]

    // ---- workspace layout ----
    float* ws     = (float*)d_ws;
    float* xc     = ws;                                    // [B,H] fp32 16MB
    float* rsum   = xc + (size_t)B_SZ * H_SZ;              // [H]
    float* cumB   = rsum + H_SZ;                           // [B]
    float* Rv     = cumB + B_SZ;                           // [B]
    float* nstep  = Rv + B_SZ;                             // [B]
    int*   halted = (int*)(nstep + B_SZ);                  // [B]
    float* dots   = (float*)(halted + B_SZ);               // [B][16] 128KB
    f16*   fh     = (f16*)(dots + (size_t)B_SZ * 16);
    f16* xh  = fh;                         // [B,D_IN]  4MB
    f16* xl  = xh  + (size_t)B_SZ * D_INN; // 4MB
    f16* sh0 = xl  + (size_t)B_SZ * D_INN; // [B,H] 8MB
    f16* sl0 = sh0 + (size_t)B_SZ * H_SZ;
    f16* sh1 = sl0 + (size_t)B_SZ * H_SZ;
    f16* sl1 = sh1 + (size_t)B_SZ * H_SZ;
    f16* Wxh = sl1 + (size_t)B_SZ * H_SZ;  // [H,D_IN] 4MB
    f16* Wxl = Wxh + (size_t)H_SZ * D_INN;
    f16* Wsh = Wxl + (size_t)H_SZ * D_INN; // [H,H] 8MB
    f16* Wsl = Wsh + (size_t)H_SZ * H_SZ;
    f16* Woh = Wsl + (size_t)H_SZ * H_SZ;  // [D_OUT,H] 4MB
    f16* Wol = Woh + (size_t)D_OUTN * H_SZ;
    f16* hidh = sh0;                       // reuse after the t-loop (aliases
    f16* hidl = sl0;                       // t=11's s_new; safe: see halt_hid)

    const dim3 blk(256);
    const dim3 gblk(512);
    const int LDW = D_INN + H_SZ;  // 3072

    // one-time fp32 -> fp16 (hi,lo) splits
    split2d<<<dim3(B_SZ * D_INN / 4 / 256), blk, 0, stream>>>(
        x, D_INN, D_INN, xh, xl, B_SZ * D_INN / 4);
    split2d<<<dim3(B_SZ * H_SZ / 4 / 256), blk, 0, stream>>>(
        h, H_SZ, H_SZ, sh0, sl0, B_SZ * H_SZ / 4);
    split2d<<<dim3(H_SZ * D_INN / 4 / 256), blk, 0, stream>>>(
        W_hidden, LDW, D_INN, Wxh, Wxl, H_SZ * D_INN / 4);
    split2d<<<dim3(H_SZ * H_SZ / 4 / 256), blk, 0, stream>>>(
        W_hidden + D_INN, LDW, H_SZ, Wsh, Wsl, H_SZ * H_SZ / 4);
    split2d<<<dim3(D_OUTN * H_SZ / 4 / 256), blk, 0, stream>>>(
        W_out, H_SZ, H_SZ, Woh, Wol, D_OUTN * H_SZ / 4);

    // rsum[j] = sum_k W_x[j,k]   (xin = x+1 correction at t==0)
    rowsum_kernel<<<dim3(H_SZ), blk, 0, stream>>>(W_hidden, LDW, D_INN, rsum);

    // grids (1-D, XCD-swizzled in-kernel; all % 8 == 0)
    const int g_step = (B_SZ / 128) * (H_SZ / 128);   // 16*16 = 256
    const int g_out  = (B_SZ / 128) * (D_OUTN / 64);  // 16*16 = 256

    // xc = x @ W_x^T + b_hidden   (loop-invariant part, fp32)
    gemm_split<128, 128, 2><<<dim3(g_step), gblk, 0, stream>>>(
        xh, xl, D_INN, Wxh, Wxl, D_INN, nullptr, b_hidden,
        xc, nullptr, nullptr, H_SZ, D_INN, H_SZ / 128, nullptr, nullptr);

    for (int t = 0; t < TMAX; ++t) {
        const f16* ph = (t & 1) ? sh1 : sh0;
        const f16* pl = (t & 1) ? sl1 : sl0;
        f16*       nh = (t & 1) ? sh0 : sh1;
        f16*       nl = (t & 1) ? sl0 : sl1;
        // s_new = s_prev @ W_s^T + xc (+ rsum at t==0); fused halt-dot partials
        gemm_split<128, 128, 2><<<dim3(g_step), gblk, 0, stream>>>(
            ph, pl, H_SZ, Wsh, Wsl, H_SZ, xc, (t == 0) ? rsum : nullptr,
            nullptr, nh, nl, H_SZ, H_SZ, H_SZ / 128, dots, w_halt);
        halt_hid<<<dim3(B_SZ), blk, 0, stream>>>(
            nh, dots, b_halt, hidden, ponder, cumB, Rv, nstep, halted,
            hidh, hidl, t);
    }

    // output = hidden @ W_out^T + b_out   (Σw = 1 ⇒ projection commutes)
    gemm_split<128, 64, 4><<<dim3(g_out), gblk, 0, stream>>>(
        hidh, hidl, H_SZ, Woh, Wol, H_SZ, nullptr, b_out,
        output, nullptr, nullptr, D_OUTN, H_SZ, D_OUTN / 64, nullptr, nullptr);
}